// Round 5
// baseline (2297.346 us; speedup 1.0000x reference)
//
#include <hip/hip_runtime.h>

#define NB 64
#define TT 512
#define DD 1024
#define HH 1024

typedef unsigned long long u64;
typedef __attribute__((ext_vector_type(4))) float f32x4;
typedef __attribute__((ext_vector_type(8))) short bf16x8;

static __device__ __forceinline__ unsigned short f2bf(float f) {
  unsigned u = __float_as_uint(f);
  unsigned r = (u + 0x7fffu + ((u >> 16) & 1u)) >> 16;
  return (unsigned short)r;
}
static __device__ __forceinline__ float bf2f(unsigned short u) {
  return __uint_as_float(((unsigned)u) << 16);
}
// tanh(x) = 1 - 2/(e^{2x}+1); e^{2x} = 2^{x*2*log2(e)}. Branch-free,
// saturates correctly at +-inf, ~1e-6 rel err (v_exp_f32 + v_rcp_f32).
static __device__ __forceinline__ float ftanh(float x) {
  float z = __builtin_amdgcn_exp2f(x * 2.8853900817779268f);
  return 1.f - 2.f * __builtin_amdgcn_rcpf(z + 1.f);
}
// async global->LDS, 16B per lane; lds dest = wave-uniform base + lane*16
static __device__ __forceinline__ void async_copy16(void* lds, const void* g) {
  __builtin_amdgcn_global_load_lds(
      (const __attribute__((address_space(1))) unsigned int*)g,
      (__attribute__((address_space(3))) unsigned int*)lds, 16, 0, 0);
}

// ---------------------------------------------------------------- prep -----
// blocks [0,nx): x fp32 -> xbf bf16, XOR-permuted global layout:
//   element (r,k): q=k>>6, e=k&63, j=e>>3 -> byte r*2048 + q*128 +
//   ((j^(r&7))<<4) + (e&7)*2   (so linear global_load_lds reproduces the
//   swizzled LDS image the MFMA fragment reads expect)
// blocks [nx, nx+1024): transpose+split Wx -> Wxh/Wxl (permuted iff fast)
// blocks [nx+1024, nx+1056): h0 fp32 -> hbuf buffer 0 (bf16)
__global__ __launch_bounds__(256) void prep_kernel(
    const float* __restrict__ x, const float* __restrict__ Wx,
    const float* __restrict__ h0, unsigned short* __restrict__ Wxh,
    unsigned short* __restrict__ Wxl, unsigned short* __restrict__ hbuf0,
    unsigned short* __restrict__ xbf, int nx, int permuted) {
  __shared__ float tile[32][33];
  int b = blockIdx.x;
  int tid = threadIdx.x;
  if (b < nx) {
    int g = b * 256 + tid;        // 0..4194303
    int r = g >> 7, jb = g & 127; // row, 8-elem block within row
    int q = jb >> 3, j = jb & 7;
    const float4* src = (const float4*)(x + r * 1024 + jb * 8);
    float4 a0 = src[0], a1 = src[1];
    uint4 o;
    o.x = (unsigned)f2bf(a0.x) | ((unsigned)f2bf(a0.y) << 16);
    o.y = (unsigned)f2bf(a0.z) | ((unsigned)f2bf(a0.w) << 16);
    o.z = (unsigned)f2bf(a1.x) | ((unsigned)f2bf(a1.y) << 16);
    o.w = (unsigned)f2bf(a1.z) | ((unsigned)f2bf(a1.w) << 16);
    *(uint4*)((char*)xbf + (size_t)r * 2048 + q * 128 + ((j ^ (r & 7)) << 4)) = o;
  } else if (b < nx + 1024) {
    int bb = b - nx;
    int tk = (bb & 31) * 32;  // k tile origin
    int tn = (bb >> 5) * 32;  // n tile origin
    int tx = tid & 31;
    int ty = tid >> 5;  // 0..7
#pragma unroll
    for (int ii = 0; ii < 4; ++ii) {
      int kk = ty + ii * 8;
      tile[kk][tx] = Wx[(tk + kk) * HH + tn + tx];  // coalesced over tx
    }
    __syncthreads();
#pragma unroll
    for (int ii = 0; ii < 4; ++ii) {
      int a = ty + ii * 8;            // n offset in tile
      float wv = tile[tx][a];         // = Wx[tk+tx][tn+a]
      unsigned short hi = f2bf(wv);
      float lo = wv - bf2f(hi);
      int c = tn + a, k = tk + tx;
      int idx;
      if (permuted) {
        int qq = k >> 6, e = k & 63, j = e >> 3;
        idx = c * 1024 + qq * 64 + ((j ^ (c & 7)) << 3) + (e & 7);
      } else {
        idx = c * 1024 + k;
      }
      Wxh[idx] = hi;
      Wxl[idx] = f2bf(lo);
    }
  } else {
    int i = (b - nx - 1024) * 256 + tid;  // 0..8191
    int n = i >> 7, cb = i & 127;
    const float4* s4 = (const float4*)(h0 + n * 1024 + cb * 8);
    float4 a0 = s4[0], a1 = s4[1];
    uint4 o;
    o.x = (unsigned)f2bf(a0.x) | ((unsigned)f2bf(a0.y) << 16);
    o.y = (unsigned)f2bf(a0.z) | ((unsigned)f2bf(a0.w) << 16);
    o.z = (unsigned)f2bf(a1.x) | ((unsigned)f2bf(a1.y) << 16);
    o.w = (unsigned)f2bf(a1.z) | ((unsigned)f2bf(a1.w) << 16);
    *(uint4*)((char*)hbuf0 + (size_t)n * 2048 + cb * 16) = o;
  }
}

// -------------------------------------------------------- xw GEMM (fast) ---
// out = bf16(x)@(Wxh+Wxl) + b.  A/B pre-swizzled in global memory; staging
// is pure global_load_lds (16B), zero VALU. m97 2-barrier structure.
__global__ __launch_bounds__(256) void xw_gemm_fast(
    const unsigned short* __restrict__ xbf,
    const unsigned short* __restrict__ Wxh,
    const unsigned short* __restrict__ Wxl, const float* __restrict__ bias,
    float* __restrict__ out) {
  __shared__ unsigned short As[128 * 64];
  __shared__ unsigned short Bh[128 * 64];
  __shared__ unsigned short Bl[128 * 64];
  int tid = threadIdx.x;
  int w = tid >> 6, lane = tid & 63;
  int n0 = blockIdx.x * 128, row0 = blockIdx.y * 128;
  int wr = w >> 1, wc = w & 1;

  f32x4 acc[4][4];
#pragma unroll
  for (int m = 0; m < 4; ++m)
#pragma unroll
    for (int n = 0; n < 4; ++n) acc[m][n] = (f32x4)0.f;

  const char* xb = (const char*)xbf;
  const char* hb = (const char*)Wxh;
  const char* lb = (const char*)Wxl;

  for (int kc = 0; kc < 16; ++kc) {  // 16 chunks of K=64
    __syncthreads();  // previous MFMA done reading LDS
#pragma unroll
    for (int i = 0; i < 4; ++i) {
      int ub = i * 4096 + w * 1024;  // wave-uniform LDS byte base
      int off = ub + lane * 16;
      int r = off >> 7, inrow = off & 127;
      async_copy16((char*)As + ub,
                   xb + (size_t)(row0 + r) * 2048 + kc * 128 + inrow);
    }
#pragma unroll
    for (int i = 0; i < 4; ++i) {
      int ub = i * 4096 + w * 1024;
      int off = ub + lane * 16;
      int c = off >> 7, inrow = off & 127;
      async_copy16((char*)Bh + ub,
                   hb + (size_t)(n0 + c) * 2048 + kc * 128 + inrow);
      async_copy16((char*)Bl + ub,
                   lb + (size_t)(n0 + c) * 2048 + kc * 128 + inrow);
    }
    asm volatile("s_waitcnt vmcnt(0)" ::: "memory");
    __syncthreads();  // all staged
#pragma unroll
    for (int kt = 0; kt < 2; ++kt) {
      int krel2 = (kt * 32 + ((lane >> 4) << 3)) * 2;  // byte offset of k
      bf16x8 af[4], bhf[4], blf[4];
#pragma unroll
      for (int m = 0; m < 4; ++m) {
        int r = wr * 64 + m * 16 + (lane & 15);
        af[m] = *(const bf16x8*)((const char*)As + r * 128 +
                                 (krel2 ^ ((r & 7) << 4)));
      }
#pragma unroll
      for (int n = 0; n < 4; ++n) {
        int c = wc * 64 + n * 16 + (lane & 15);
        int off = c * 128 + (krel2 ^ ((c & 7) << 4));
        bhf[n] = *(const bf16x8*)((const char*)Bh + off);
        blf[n] = *(const bf16x8*)((const char*)Bl + off);
      }
#pragma unroll
      for (int m = 0; m < 4; ++m)
#pragma unroll
        for (int n = 0; n < 4; ++n) {
          acc[m][n] = __builtin_amdgcn_mfma_f32_16x16x32_bf16(af[m], bhf[n],
                                                              acc[m][n], 0, 0, 0);
          acc[m][n] = __builtin_amdgcn_mfma_f32_16x16x32_bf16(af[m], blf[n],
                                                              acc[m][n], 0, 0, 0);
        }
    }
  }

#pragma unroll
  for (int n = 0; n < 4; ++n) {
    int col = n0 + wc * 64 + n * 16 + (lane & 15);
    float bv = bias[col];
#pragma unroll
    for (int m = 0; m < 4; ++m) {
      int rbase = row0 + wr * 64 + m * 16 + ((lane >> 4) << 2);
#pragma unroll
      for (int i = 0; i < 4; ++i)
        out[(size_t)(rbase + i) * HH + col] = acc[m][n][i] + bv;
    }
  }
}

// -------------------------------------------------------- xw GEMM (slow) ---
// Fallback when ws too small for xbf: reg-staged with in-kernel convert.
__global__ __launch_bounds__(256) void xw_gemm_slow(
    const float* __restrict__ x, const unsigned short* __restrict__ Wxh,
    const unsigned short* __restrict__ Wxl, const float* __restrict__ bias,
    float* __restrict__ out) {
  __shared__ unsigned short As[128 * 64];
  __shared__ unsigned short Bh[128 * 64];
  __shared__ unsigned short Bl[128 * 64];

  int tid = threadIdx.x;
  int n0 = blockIdx.x * 128;
  int row0 = blockIdx.y * 128;
  int w = tid >> 6, lane = tid & 63;
  int wr = w >> 1, wc = w & 1;

  f32x4 acc[4][4];
#pragma unroll
  for (int m = 0; m < 4; ++m)
#pragma unroll
    for (int n = 0; n < 4; ++n) acc[m][n] = (f32x4)0.f;

  for (int kk = 0; kk < DD; kk += 64) {
    float4 av[8];
#pragma unroll
    for (int i = 0; i < 8; ++i) {
      int lin = tid + 256 * i;
      int r = lin >> 4, kq = lin & 15;
      av[i] = *(const float4*)(x + (size_t)(row0 + r) * DD + kk + kq * 4);
    }
    int4 bhv[4], blv[4];
#pragma unroll
    for (int i = 0; i < 4; ++i) {
      int lin = tid + 256 * i;
      int c = lin >> 3, kb = lin & 7;
      bhv[i] = *(const int4*)(Wxh + (size_t)(n0 + c) * DD + kk + kb * 8);
      blv[i] = *(const int4*)(Wxl + (size_t)(n0 + c) * DD + kk + kb * 8);
    }
    __syncthreads();
#pragma unroll
    for (int i = 0; i < 8; ++i) {
      int lin = tid + 256 * i;
      int r = lin >> 4, kq = lin & 15;
      uint2 u;
      u.x = (unsigned)f2bf(av[i].x) | ((unsigned)f2bf(av[i].y) << 16);
      u.y = (unsigned)f2bf(av[i].z) | ((unsigned)f2bf(av[i].w) << 16);
      *(uint2*)((char*)As + r * 128 + ((kq * 8) ^ ((r & 7) << 4))) = u;
    }
#pragma unroll
    for (int i = 0; i < 4; ++i) {
      int lin = tid + 256 * i;
      int c = lin >> 3, kb = lin & 7;
      int off = c * 128 + ((kb * 16) ^ ((c & 7) << 4));
      *(int4*)((char*)Bh + off) = bhv[i];
      *(int4*)((char*)Bl + off) = blv[i];
    }
    __syncthreads();
#pragma unroll
    for (int kt = 0; kt < 2; ++kt) {
      int krel2 = (kt * 32 + ((lane >> 4) << 3)) * 2;
      bf16x8 af[4], bhf[4], blf[4];
#pragma unroll
      for (int m = 0; m < 4; ++m) {
        int r = wr * 64 + m * 16 + (lane & 15);
        af[m] = *(const bf16x8*)((const char*)As + r * 128 +
                                 (krel2 ^ ((r & 7) << 4)));
      }
#pragma unroll
      for (int n = 0; n < 4; ++n) {
        int c = wc * 64 + n * 16 + (lane & 15);
        int off = c * 128 + (krel2 ^ ((c & 7) << 4));
        bhf[n] = *(const bf16x8*)((const char*)Bh + off);
        blf[n] = *(const bf16x8*)((const char*)Bl + off);
      }
#pragma unroll
      for (int m = 0; m < 4; ++m)
#pragma unroll
        for (int n = 0; n < 4; ++n) {
          acc[m][n] = __builtin_amdgcn_mfma_f32_16x16x32_bf16(af[m], bhf[n],
                                                              acc[m][n], 0, 0, 0);
          acc[m][n] = __builtin_amdgcn_mfma_f32_16x16x32_bf16(af[m], blf[n],
                                                              acc[m][n], 0, 0, 0);
        }
    }
    __syncthreads();
  }

#pragma unroll
  for (int n = 0; n < 4; ++n) {
    int col = n0 + wc * 64 + n * 16 + (lane & 15);
    float bv = bias[col];
#pragma unroll
    for (int m = 0; m < 4; ++m) {
      int rbase = row0 + wr * 64 + m * 16 + ((lane >> 4) << 2);
#pragma unroll
      for (int i = 0; i < 4; ++i)
        out[(size_t)(rbase + i) * HH + col] = acc[m][n][i] + bv;
    }
  }
}

// ---------------------------------------------------------------- scan -----
// Per-wave flag protocol, minimal serial chain per step:
//   poll(t): each lane polls one of the 64 wave-flags of its group
//   -> batched h loads (agent scope) -> MFMA -> LDS reduce-write
//   -> lgkm-ONLY barrier (vmem stays in flight) -> reduce-read -> tanh
//   -> h-store -> per-wave s_waitcnt vmcnt(0) -> lane0 publishes wave flag
//   -> deferred out-store(t-1) + xw prefetch(t+2)  (fly during next poll).
// Safety: full 64-flag poll(t) implies every wave finished step t-1, hence
// all reads of h buffer (t+1)&1 are done before anyone overwrites it.
__global__ __launch_bounds__(256) void rnn_scan(
    const float* __restrict__ Wh, float* __restrict__ out,
    unsigned short* __restrict__ hbuf, unsigned* __restrict__ flags) {
  int tid = threadIdx.x;
  int w = tid >> 6, lane = tid & 63;
  int p = blockIdx.x >> 4;  // batch group 0..3
  int q = blockIdx.x & 15;  // col group 0..15
  int n0 = p * 16;
  int c0 = q * 64;

  __shared__ float red[2][4][16][68];

  // ---- Wh hi/lo fragments resident in VGPRs/AGPRs, MFMA B-layout ----
  bf16x8 whi[4][8], wlo[4][8];
#pragma unroll
  for (int ct = 0; ct < 4; ++ct) {
#pragma unroll
    for (int kt = 0; kt < 8; ++kt) {
      int c = c0 + ct * 16 + (lane & 15);
      int kb = w * 256 + kt * 32 + ((lane >> 4) << 3);
#pragma unroll
      for (int j = 0; j < 8; ++j) {
        float wf = Wh[(size_t)(kb + j) * HH + c];
        unsigned short hi = f2bf(wf);
        whi[ct][kt][j] = (short)hi;
        wlo[ct][kt][j] = (short)f2bf(wf - bf2f(hi));
      }
    }
  }

  int erow_l = tid >> 4;  // 0..15
  int erow = n0 + erow_l;
  int ecol = c0 + ((tid & 15) << 2);
  size_t obase = (size_t)erow * (TT * HH) + ecol;
  int hbase = erow * HH + ecol;
  int abase = (n0 + (lane & 15)) * HH + w * 256 + ((lane >> 4) << 3);

  unsigned* myflag = flags + p * 64 + q * 4 + w;  // this wave's flag
  const unsigned* pollp = flags + p * 64 + lane;  // one flag per lane

  float4 xw0 = *(const float4*)(out + obase);        // xw for t=0
  float4 xw1 = *(const float4*)(out + obase + HH);   // xw for t=1
  float4 prev_hv = make_float4(0.f, 0.f, 0.f, 0.f);

  for (int t = 0; t < TT; ++t) {
    const unsigned short* hp = hbuf + (t & 1) * (NB * HH);
    unsigned short* hn = hbuf + ((t + 1) & 1) * (NB * HH);

    if (t > 0) {  // wait until every wave of the group published step t
      unsigned tg = (unsigned)t;
      for (;;) {
        unsigned v = __hip_atomic_load(pollp, __ATOMIC_RELAXED,
                                       __HIP_MEMORY_SCOPE_AGENT);
        if (__all((int)(v >= tg))) break;
        __builtin_amdgcn_s_sleep(1);
      }
      asm volatile("" ::: "memory");
    }

    // ---- h loads (agent scope, coherent), batched: one RTT ----
    const u64* hq = (const u64*)(hp + abase);
    u64 pu[8][2];
#pragma unroll
    for (int kt = 0; kt < 8; ++kt) {
      pu[kt][0] = __hip_atomic_load(hq + kt * 8, __ATOMIC_RELAXED,
                                    __HIP_MEMORY_SCOPE_AGENT);
      pu[kt][1] = __hip_atomic_load(hq + kt * 8 + 1, __ATOMIC_RELAXED,
                                    __HIP_MEMORY_SCOPE_AGENT);
    }

    f32x4 acc[4];
#pragma unroll
    for (int ct = 0; ct < 4; ++ct) acc[ct] = (f32x4)0.f;
#pragma unroll
    for (int kt = 0; kt < 8; ++kt) {
      union { u64 u[2]; bf16x8 v; } pk;
      pk.u[0] = pu[kt][0];
      pk.u[1] = pu[kt][1];
#pragma unroll
      for (int ct = 0; ct < 4; ++ct) {
        acc[ct] = __builtin_amdgcn_mfma_f32_16x16x32_bf16(pk.v, whi[ct][kt],
                                                          acc[ct], 0, 0, 0);
        acc[ct] = __builtin_amdgcn_mfma_f32_16x16x32_bf16(pk.v, wlo[ct][kt],
                                                          acc[ct], 0, 0, 0);
      }
    }

    // ---- split-K reduce across the 4 waves ----
    int db = t & 1;
    int rr = (lane >> 4) << 2, cc = lane & 15;
#pragma unroll
    for (int ct = 0; ct < 4; ++ct)
#pragma unroll
      for (int i = 0; i < 4; ++i) red[db][w][rr + i][ct * 16 + cc] = acc[ct][i];
    // lgkm-only barrier: vmem (xw prefetch, out-store) stays in flight
    asm volatile("s_waitcnt lgkmcnt(0)" ::: "memory");
    __builtin_amdgcn_s_barrier();
    asm volatile("" ::: "memory");

    int c4 = (tid & 15) << 2;
    float4 s = make_float4(0.f, 0.f, 0.f, 0.f);
#pragma unroll
    for (int ww = 0; ww < 4; ++ww) {
      float4 v = *(const float4*)&red[db][ww][erow_l][c4];
      s.x += v.x; s.y += v.y; s.z += v.z; s.w += v.w;
    }
    float4 hv;
    hv.x = ftanh(s.x + xw0.x);
    hv.y = ftanh(s.y + xw0.y);
    hv.z = ftanh(s.z + xw0.z);
    hv.w = ftanh(s.w + xw0.w);

    if (t + 1 < TT) {
      // h for next step: 4 bf16 -> ONE 8B agent-scope store
      unsigned lo32 = (unsigned)f2bf(hv.x) | ((unsigned)f2bf(hv.y) << 16);
      unsigned hi32 = (unsigned)f2bf(hv.z) | ((unsigned)f2bf(hv.w) << 16);
      __hip_atomic_store((u64*)(hn + hbase), ((u64)hi32 << 32) | lo32,
                         __ATOMIC_RELAXED, __HIP_MEMORY_SCOPE_AGENT);
      // per-wave publish: only the h-store is fresh in vmcnt here
      asm volatile("s_waitcnt vmcnt(0)" ::: "memory");
      if (lane == 0)
        __hip_atomic_store(myflag, (unsigned)(t + 1), __ATOMIC_RELAXED,
                           __HIP_MEMORY_SCOPE_AGENT);
    }

    // off-chain vmem: in flight across next poll, drained >=1 step later
    if (t > 0) *(float4*)(out + obase + (size_t)(t - 1) * HH) = prev_hv;
    prev_hv = hv;
    float4 xwf = make_float4(0.f, 0.f, 0.f, 0.f);
    if (t + 2 < TT) xwf = *(const float4*)(out + obase + (size_t)(t + 2) * HH);
    xw0 = xw1;
    xw1 = xwf;
  }
  *(float4*)(out + obase + (size_t)(TT - 1) * HH) = prev_hv;
}

// ------------------------------------------------------------- launch ------
extern "C" void kernel_launch(void* const* d_in, const int* in_sizes, int n_in,
                              void* d_out, int out_size, void* d_ws,
                              size_t ws_size, hipStream_t stream) {
  const float* x = (const float*)d_in[0];
  const float* h0 = (const float*)d_in[1];
  const float* Wx = (const float*)d_in[2];
  const float* Wh = (const float*)d_in[3];
  const float* b = (const float*)d_in[4];
  float* out = (float*)d_out;

  char* ws = (char*)d_ws;
  unsigned* flags = (unsigned*)ws;                            // 4 KB
  unsigned short* hbuf = (unsigned short*)(ws + 4096);        // 256 KB (2 bufs)
  unsigned short* Wxh = (unsigned short*)(ws + 266240);       // 2 MB
  unsigned short* Wxl = (unsigned short*)(ws + 2363392);      // 2 MB
  unsigned short* xbf = (unsigned short*)(ws + 4460544);      // 64 MB

  int fast = (ws_size >= 71569408ULL) ? 1 : 0;
  int nx = fast ? 16384 : 0;

  hipMemsetAsync(flags, 0, 4096, stream);
  prep_kernel<<<nx + 1056, 256, 0, stream>>>(x, Wx, h0, Wxh, Wxl, hbuf, xbf,
                                             nx, fast);
  if (fast)
    xw_gemm_fast<<<dim3(8, 256), 256, 0, stream>>>(xbf, Wxh, Wxl, b, out);
  else
    xw_gemm_slow<<<dim3(8, 256), 256, 0, stream>>>(x, Wxh, Wxl, b, out);
  rnn_scan<<<64, 256, 0, stream>>>(Wh, out, hbuf, flags);
}